// Round 5
// baseline (761.238 us; speedup 1.0000x reference)
//
#include <hip/hip_runtime.h>

// ---------------- problem constants ----------------
// B*P=32, N=512, D=128, H=4, DK=32, T=3 (transition matrices {0,1,3})
// Inputs f32. OUTPUT IS F32 (R4 post-mortem: bit-identical absmax across
// R2/R3/R4 despite structural changes proves the compute was right and the
// output dtype was wrong — we were writing u16 bf16 codes into an f32 buffer).
// LDS < 64KB per kernel (R2 lesson). ws use = 24MB.

typedef __attribute__((ext_vector_type(8))) short  short8;
typedef __attribute__((ext_vector_type(4))) float  floatx4;

#define WS_NEED 25165824ull   // 3 * 4,194,304 (q,k,v) + 12,582,912 (att)

__device__ __forceinline__ float b2f(unsigned short u) {
    union { unsigned int i; float f; } v; v.i = ((unsigned int)u) << 16; return v.f;
}
__device__ __forceinline__ unsigned short f2b(float f) {
    union { float f; unsigned int i; } v; v.f = f;
    unsigned int x = v.i;
    return (unsigned short)((x + 0x7fffu + ((x >> 16) & 1u)) >> 16);
}
// convert 8 consecutive f32 (32B-aligned) to a short8 of bf16
__device__ __forceinline__ short8 cvt8(const float* p) {
    floatx4 a = *(const floatx4*)p;
    floatx4 b = *(const floatx4*)(p + 4);
    short8 r;
    r[0] = (short)f2b(a[0]); r[1] = (short)f2b(a[1]);
    r[2] = (short)f2b(a[2]); r[3] = (short)f2b(a[3]);
    r[4] = (short)f2b(b[0]); r[5] = (short)f2b(b[1]);
    r[6] = (short)f2b(b[2]); r[7] = (short)f2b(b[3]);
    return r;
}

// ---------------- K1: QKV projection for ONE t (MFMA bf16) ----------------
// grid (bp=32, mt=4); LDS = Xs (32KB). W B-frags direct from global (L2-hot).
__global__ __launch_bounds__(256) void k_qkv(
    const float* __restrict__ X,             // [32][512][128] f32
    const float* __restrict__ Wq,            // [128][128] f32 (already offset to t)
    const float* __restrict__ Wk,
    const float* __restrict__ Wv,
    unsigned short* __restrict__ q_ws,       // [32][512][128] bf16
    unsigned short* __restrict__ k_ws,
    unsigned short* __restrict__ v_ws)
{
    int bp = blockIdx.x;
    int mt = blockIdx.y;
    __shared__ unsigned short Xs[128 * 128];     // 32 KB
    int tid = threadIdx.x;
    int lane = tid & 63, wv = tid >> 6;
    int l15 = lane & 15, quad = lane >> 4;

    const float* Xbase = X + ((size_t)bp * 512 + mt * 128) * 128;
    for (int i = 0; i < 8; ++i) {
        int e = (i * 256 + tid) * 8;
        *(short8*)&Xs[e] = cvt8(&Xbase[e]);
    }
    __syncthreads();

    const float* Wsel[3] = { Wq, Wk, Wv };
    unsigned short* Osel[3] = { q_ws, k_ws, v_ws };

    for (int qkv = 0; qkv < 3; ++qkv) {
        const float* Wb = Wsel[qkv];
        unsigned short* Ob = Osel[qkv] + ((size_t)bp * 512 + mt * 128) * 128;
        for (int ct = 0; ct < 8; ++ct) {
            short8 bfr[4];
            for (int kk = 0; kk < 4; ++kk)
                bfr[kk] = cvt8(&Wb[(size_t)(ct * 16 + l15) * 128 + kk * 32 + quad * 8]);
            floatx4 acc0 = {0.f, 0.f, 0.f, 0.f};
            floatx4 acc1 = {0.f, 0.f, 0.f, 0.f};
            int rt0 = wv * 2, rt1 = wv * 2 + 1;
            for (int kk = 0; kk < 4; ++kk) {
                short8 a0 = *(const short8*)&Xs[(rt0 * 16 + l15) * 128 + kk * 32 + quad * 8];
                short8 a1 = *(const short8*)&Xs[(rt1 * 16 + l15) * 128 + kk * 32 + quad * 8];
                acc0 = __builtin_amdgcn_mfma_f32_16x16x32_bf16(a0, bfr[kk], acc0, 0, 0, 0);
                acc1 = __builtin_amdgcn_mfma_f32_16x16x32_bf16(a1, bfr[kk], acc1, 0, 0, 0);
            }
            int col = ct * 16 + l15;
            for (int i = 0; i < 4; ++i) {
                Ob[(size_t)(rt0 * 16 + quad * 4 + i) * 128 + col] = f2b(acc0[i]);
                Ob[(size_t)(rt1 * 16 + quad * 4 + i) * 128 + col] = f2b(acc1[i]);
            }
        }
    }
}

// ---------------- K2: sparse masked attention for ONE t ----------------
// grid (bp=32, z=16: h=z&3, chunk=z>>2); wave-per-row, 32 rows/wave.
// Inline tm-row compaction (ballot) -> LDS midx/tmw.
// LDS = Ks 32KB + wbuf 8KB + tmw 8KB + midx 4KB = 52KB.
__global__ __launch_bounds__(256) void k_attn(
    const unsigned short* __restrict__ q_ws,   // [32][512][128] bf16
    const unsigned short* __restrict__ k_ws,
    const unsigned short* __restrict__ v_ws,
    const float* __restrict__ tmrow0,          // tm[tsel]: [512][512] f32
    unsigned short* __restrict__ att_ws,       // [32][512][384] bf16
    int toff)                                  // t*128
{
    int bp = blockIdx.x;
    int h = blockIdx.z & 3;
    int chunk = blockIdx.z >> 2;
    __shared__ unsigned short Ks[512 * 32];
    __shared__ float          wbuf[4][512];
    __shared__ float          tmw[4][512];
    __shared__ unsigned short midx[4][512];

    int tid = threadIdx.x, lane = tid & 63, wv = tid >> 6;
    size_t tb = (size_t)bp * 512;

    const unsigned short* Kg = k_ws + tb * 128 + h * 32;
    for (int i = 0; i < 8; ++i) {
        int flat = i * 256 + tid;            // 0..2047
        int m = flat >> 2, seg = flat & 3;
        *(short8*)&Ks[m * 32 + seg * 8] = *(const short8*)&Kg[(size_t)m * 128 + seg * 8];
    }
    __syncthreads();

    const float inv_sqrt_dk = 0.17677669529663687f;
    int k31 = lane & 31;
    const unsigned short* Vg = v_ws + tb * 128 + h * 32;

    for (int r = 0; r < 32; ++r) {
        int n = chunk * 128 + wv * 32 + r;
        float q = b2f(q_ws[(tb + n) * 128 + h * 32 + k31]);   // lanes 0..31 hold Q[n][k]
        const float* tmrow = tmrow0 + (size_t)n * 512;

        // inline compaction of this tm row (order-preserving ballot scan)
        int nnz = 0;
        for (int it = 0; it < 8; ++it) {
            int m = it * 64 + lane;
            float v = tmrow[m];
            unsigned long long mask = __ballot(v != 0.0f);
            if (v != 0.0f) {
                int pos = nnz + __popcll(mask & ((1ull << lane) - 1ull));
                midx[wv][pos] = (unsigned short)m;
                tmw[wv][pos] = v;
            }
            nnz += __popcll(mask);
        }
        int itmax = (nnz + 63) >> 6;

        // pass A: scores for the nnz gathered columns
        float smax = -3.0e38f;
        for (int it = 0; it < itmax; ++it) {
            int j = it * 64 + lane;
            bool act = j < nnz;
            int m = act ? (int)midx[wv][j] : 0;
            float s = 0.f;
            for (int c = 0; c < 4; ++c) {
                short8 kv8 = *(const short8*)&Ks[m * 32 + c * 8];
                #pragma unroll
                for (int e = 0; e < 8; ++e) {
                    float kf = b2f((unsigned short)kv8[e]);
                    float qk = __shfl(q, c * 8 + e, 64);
                    s += qk * kf;
                }
            }
            s *= inv_sqrt_dk;
            if (act) {
                wbuf[wv][j] = s;
                smax = fmaxf(smax, s);
            }
        }
        for (int d = 1; d < 64; d <<= 1) smax = fmaxf(smax, __shfl_xor(smax, d, 64));

        // pass B: exp, Z, weight by tm value (alpha*tm, unnormalized)
        float zsum = 0.f;
        for (int it = 0; it < itmax; ++it) {
            int j = it * 64 + lane;
            if (j < nnz) {
                float e = __expf(wbuf[wv][j] - smax);
                zsum += e;
                wbuf[wv][j] = e * tmw[wv][j];
            }
        }
        for (int d = 1; d < 64; d <<= 1) zsum += __shfl_xor(zsum, d, 64);
        float inv_z = (zsum > 0.f) ? (1.0f / zsum) : 0.f;

        // pass C: PV gather from global v_ws; halves split j, lanes 0..31 = k
        int half = lane >> 5;
        float acc = 0.f;
        for (int j = half; j < nnz; j += 2) {
            float w = wbuf[wv][j];
            int m = midx[wv][j];
            acc += w * b2f(Vg[(size_t)m * 128 + k31]);
        }
        acc += __shfl_down(acc, 32, 64);
        if (lane < 32) {
            att_ws[(tb + n) * 384 + toff + h * 32 + k31] = f2b(acc * inv_z);
        }
    }
}

// ---------------- K3: out-projection (MFMA) + residual + LayerNorm ----------------
// grid (bp=32, mt=8); LDS = As(16KB) + Ws(32KB) = 48KB. OUTPUT = F32.
__global__ __launch_bounds__(256) void k_oproj(
    const unsigned short* __restrict__ att_ws,   // [32][512][384] bf16
    const float* __restrict__ Wo,                // [128][384] f32
    const float* __restrict__ X,                 // [32][512][128] f32 (residual)
    const float* __restrict__ gamma,
    const float* __restrict__ beta,
    float* __restrict__ out,                     // [32][512][128] f32
    float sentinel)                              // 0 normally; 1024 if ws too small
{
    int bp = blockIdx.x;
    int mt = blockIdx.y;
    __shared__ unsigned short As[64 * 128];
    __shared__ unsigned short Ws[128 * 128];
    int tid = threadIdx.x, lane = tid & 63, wv = tid >> 6;
    int l15 = lane & 15, quad = lane >> 4;

    floatx4 acc[8];
    for (int ct = 0; ct < 8; ++ct) acc[ct] = (floatx4){0.f, 0.f, 0.f, 0.f};

    size_t rowbase = (size_t)bp * 512 + mt * 64;

    for (int kc = 0; kc < 3; ++kc) {
        __syncthreads();
        for (int i = 0; i < 4; ++i) {            // As: 64x128 (bf16 copy)
            int flat = i * 256 + tid;            // 0..1023
            int row = flat >> 4, colg = (flat & 15) * 8;
            *(short8*)&As[row * 128 + colg] =
                *(const short8*)&att_ws[(rowbase + row) * 384 + kc * 128 + colg];
        }
        for (int i = 0; i < 8; ++i) {            // Ws: 128x128 chunk of Wo (f32 -> bf16)
            int flat = i * 256 + tid;            // 0..2047
            int row = flat >> 4, colg = (flat & 15) * 8;
            *(short8*)&Ws[row * 128 + colg] = cvt8(&Wo[(size_t)row * 384 + kc * 128 + colg]);
        }
        __syncthreads();
        for (int ct = 0; ct < 8; ++ct) {
            for (int kk = 0; kk < 4; ++kk) {
                short8 a = *(const short8*)&As[(wv * 16 + l15) * 128 + kk * 32 + quad * 8];
                short8 b = *(const short8*)&Ws[(ct * 16 + l15) * 128 + kk * 32 + quad * 8];
                acc[ct] = __builtin_amdgcn_mfma_f32_16x16x32_bf16(a, b, acc[ct], 0, 0, 0);
            }
        }
    }

    // epilogue: residual + LayerNorm. wave wv owns rows mt*64 + wv*16 + (quad*4+i)
    for (int i = 0; i < 4; ++i) {
        int lrow = wv * 16 + quad * 4 + i;
        size_t grow = rowbase + lrow;
        float vals[8];
        float s = 0.f, sq = 0.f;
        for (int ct = 0; ct < 8; ++ct) {
            int col = ct * 16 + l15;
            float v = acc[ct][i] + X[grow * 128 + col];
            vals[ct] = v;
            s += v; sq += v * v;
        }
        for (int d = 1; d < 16; d <<= 1) {
            s  += __shfl_xor(s, d, 64);
            sq += __shfl_xor(sq, d, 64);
        }
        float mu = s * (1.0f / 128.0f);
        float var = sq * (1.0f / 128.0f) - mu * mu;
        float rs = rsqrtf(var + 1e-5f);
        for (int ct = 0; ct < 8; ++ct) {
            int col = ct * 16 + l15;
            float g = gamma[col], bb = beta[col];
            out[grow * 128 + col] = (vals[ct] - mu) * rs * g + bb + sentinel;  // F32 write
        }
    }
}

// ---------------- launcher ----------------
extern "C" void kernel_launch(void* const* d_in, const int* in_sizes, int n_in,
                              void* d_out, int out_size, void* d_ws, size_t ws_size,
                              hipStream_t stream) {
    const float* X     = (const float*)d_in[0];
    // d_in[1] = c_inputs (unused by the reference)
    const float* TM    = (const float*)d_in[2];
    const float* Wq    = (const float*)d_in[3];
    const float* Wk    = (const float*)d_in[4];
    const float* Wv    = (const float*)d_in[5];
    const float* Wo    = (const float*)d_in[6];
    const float* gamma = (const float*)d_in[7];
    const float* beta  = (const float*)d_in[8];
    float* out = (float*)d_out;   // reference output dtype is float32

    char* ws = (char*)d_ws;
    // per-t reused q/k/v (bf16 [32][512][128] each = 4,194,304 B), then att.
    unsigned short* q_ws   = (unsigned short*)(ws);
    unsigned short* k_ws   = (unsigned short*)(ws + 4194304);
    unsigned short* v_ws   = (unsigned short*)(ws + 8388608);
    unsigned short* att_ws = (unsigned short*)(ws + 12582912);  // [32][512][384] = 12,582,912 B

    const int tsel[3] = {0, 1, 3};
    for (int t = 0; t < 3; ++t) {
        k_qkv<<<dim3(32, 4), 256, 0, stream>>>(
            X, Wq + (size_t)t * 16384, Wk + (size_t)t * 16384, Wv + (size_t)t * 16384,
            q_ws, k_ws, v_ws);
        k_attn<<<dim3(32, 1, 16), 256, 0, stream>>>(
            q_ws, k_ws, v_ws, TM + (size_t)tsel[t] * 512 * 512, att_ws, t * 128);
    }
    float sentinel = (ws_size < WS_NEED) ? 1024.0f : 0.0f;
    k_oproj<<<dim3(32, 8), 256, 0, stream>>>(att_ws, Wo, X, gamma, beta, out, sentinel);
}

// Round 6
// 502.878 us; speedup vs baseline: 1.5138x; 1.5138x over previous
//
#include <hip/hip_runtime.h>

// ---------------- problem constants ----------------
// B*P=32, N=512, D=128, H=4, DK=32, T=3 (transition matrices {0,1,3})
// Inputs f32, OUTPUT f32. LDS < 64KB per kernel. ws use = 24MB (validated).
// R5: k_attn was latency-bound (VALUBusy 14.7%, 17k cyc/row): per-row shfl
// chains, 128x redundant tm compaction, LDS bank conflicts on random K rows.
// This round: block-per-n k_attn, compaction once/n, shfl-free score loop.

typedef __attribute__((ext_vector_type(8))) short  short8;
typedef __attribute__((ext_vector_type(4))) float  floatx4;

#define WS_NEED 25165824ull   // 3 * 4,194,304 (q,k,v) + 12,582,912 (att)

__device__ __forceinline__ float b2f(unsigned short u) {
    union { unsigned int i; float f; } v; v.i = ((unsigned int)u) << 16; return v.f;
}
__device__ __forceinline__ unsigned short f2b(float f) {
    union { float f; unsigned int i; } v; v.f = f;
    unsigned int x = v.i;
    return (unsigned short)((x + 0x7fffu + ((x >> 16) & 1u)) >> 16);
}
__device__ __forceinline__ short8 cvt8(const float* p) {
    floatx4 a = *(const floatx4*)p;
    floatx4 b = *(const floatx4*)(p + 4);
    short8 r;
    r[0] = (short)f2b(a[0]); r[1] = (short)f2b(a[1]);
    r[2] = (short)f2b(a[2]); r[3] = (short)f2b(a[3]);
    r[4] = (short)f2b(b[0]); r[5] = (short)f2b(b[1]);
    r[6] = (short)f2b(b[2]); r[7] = (short)f2b(b[3]);
    return r;
}

// ---------------- K1: QKV projection for ONE t (MFMA bf16) ----------------
__global__ __launch_bounds__(256) void k_qkv(
    const float* __restrict__ X,             // [32][512][128] f32
    const float* __restrict__ Wq,            // [128][128] f32 (offset to t)
    const float* __restrict__ Wk,
    const float* __restrict__ Wv,
    unsigned short* __restrict__ q_ws,       // [32][512][128] bf16
    unsigned short* __restrict__ k_ws,
    unsigned short* __restrict__ v_ws)
{
    int bp = blockIdx.x;
    int mt = blockIdx.y;
    __shared__ unsigned short Xs[128 * 128];     // 32 KB
    int tid = threadIdx.x;
    int lane = tid & 63, wv = tid >> 6;
    int l15 = lane & 15, quad = lane >> 4;

    const float* Xbase = X + ((size_t)bp * 512 + mt * 128) * 128;
    for (int i = 0; i < 8; ++i) {
        int e = (i * 256 + tid) * 8;
        *(short8*)&Xs[e] = cvt8(&Xbase[e]);
    }
    __syncthreads();

    const float* Wsel[3] = { Wq, Wk, Wv };
    unsigned short* Osel[3] = { q_ws, k_ws, v_ws };

    for (int qkv = 0; qkv < 3; ++qkv) {
        const float* Wb = Wsel[qkv];
        unsigned short* Ob = Osel[qkv] + ((size_t)bp * 512 + mt * 128) * 128;
        for (int ct = 0; ct < 8; ++ct) {
            short8 bfr[4];
            for (int kk = 0; kk < 4; ++kk)
                bfr[kk] = cvt8(&Wb[(size_t)(ct * 16 + l15) * 128 + kk * 32 + quad * 8]);
            floatx4 acc0 = {0.f, 0.f, 0.f, 0.f};
            floatx4 acc1 = {0.f, 0.f, 0.f, 0.f};
            int rt0 = wv * 2, rt1 = wv * 2 + 1;
            for (int kk = 0; kk < 4; ++kk) {
                short8 a0 = *(const short8*)&Xs[(rt0 * 16 + l15) * 128 + kk * 32 + quad * 8];
                short8 a1 = *(const short8*)&Xs[(rt1 * 16 + l15) * 128 + kk * 32 + quad * 8];
                acc0 = __builtin_amdgcn_mfma_f32_16x16x32_bf16(a0, bfr[kk], acc0, 0, 0, 0);
                acc1 = __builtin_amdgcn_mfma_f32_16x16x32_bf16(a1, bfr[kk], acc1, 0, 0, 0);
            }
            int col = ct * 16 + l15;
            for (int i = 0; i < 4; ++i) {
                Ob[(size_t)(rt0 * 16 + quad * 4 + i) * 128 + col] = f2b(acc0[i]);
                Ob[(size_t)(rt1 * 16 + quad * 4 + i) * 128 + col] = f2b(acc1[i]);
            }
        }
    }
}

// ---------------- K2: sparse masked attention for ONE t (block per n) ----------
// grid (n=512), block 512 (8 waves). Compaction once per n (8-way parallel).
// Qs staged as pre-scaled f32 (conflict-free broadcasts, no shfl in score loop).
// Wave wv handles 16 instances (bp = ii*2 + (wv>>2), h = wv&3).
// LDS: Qs 16KB + midx 1KB + tmw 2KB + wls 16KB + seg ~0.1KB = ~35KB.
__global__ __launch_bounds__(512) void k_attn(
    const unsigned short* __restrict__ q_ws,   // [32][512][128] bf16
    const unsigned short* __restrict__ k_ws,
    const unsigned short* __restrict__ v_ws,
    const float* __restrict__ tmrow0,          // tm[tsel]: [512][512] f32
    unsigned short* __restrict__ att_ws,       // [32][512][384] bf16
    int toff)                                  // t*128
{
    int n = blockIdx.x;
    __shared__ float          Qs[32][128];     // f32, pre-scaled by 1/sqrt(dk)
    __shared__ unsigned short midx[512];
    __shared__ float          tmw[512];
    __shared__ float          wls[8][512];
    __shared__ int            segcnt[8];

    int tid = threadIdx.x, lane = tid & 63, wv = tid >> 6;   // wv 0..7
    const float inv_sqrt_dk = 0.17677669529663687f;

    // --- compaction phase 1: wave wv ballots segment wv of tm row n
    const float* tmrow = tmrow0 + (size_t)n * 512;
    float tv = tmrow[wv * 64 + lane];
    unsigned long long bmask = __ballot(tv != 0.0f);
    if (lane == 0) segcnt[wv] = __popcll(bmask);

    // --- stage Qs (all 512 threads): bp = tid>>4, 8 elems each
    {
        int bp = tid >> 4, seg = tid & 15;
        short8 qv = *(const short8*)&q_ws[((size_t)bp * 512 + n) * 128 + seg * 8];
        #pragma unroll
        for (int e = 0; e < 8; ++e)
            Qs[bp][seg * 8 + e] = b2f((unsigned short)qv[e]) * inv_sqrt_dk;
    }
    __syncthreads();

    // --- compaction phase 2: prefix offsets, scatter midx/tmw
    int off = 0, nnz = 0;
    #pragma unroll
    for (int s = 0; s < 8; ++s) {
        int c = segcnt[s];
        if (s < wv) off += c;
        nnz += c;
    }
    if (tv != 0.0f) {
        int pos = off + __popcll(bmask & ((1ull << lane) - 1ull));
        midx[pos] = (unsigned short)(wv * 64 + lane);
        tmw[pos] = tv;
    }
    __syncthreads();

    int itmax = (nnz + 63) >> 6;
    int h = wv & 3;
    int k31 = lane & 31, half = lane >> 5;

    for (int ii = 0; ii < 16; ++ii) {
        int bp = ii * 2 + (wv >> 2);
        const unsigned short* Kb = k_ws + (size_t)bp * 512 * 128 + h * 32;
        const unsigned short* Vb = v_ws + (size_t)bp * 512 * 128 + h * 32;

        // q row into registers (LDS broadcast reads, conflict-free)
        floatx4 qv[8];
        #pragma unroll
        for (int c = 0; c < 8; ++c) qv[c] = *(const floatx4*)&Qs[bp][h * 32 + c * 4];

        // pass A: scores for compacted columns
        float smax = -3.0e38f;
        for (int it = 0; it < itmax; ++it) {
            int j = it * 64 + lane;
            bool act = j < nnz;
            int m = act ? (int)midx[j] : (int)midx[0];
            const unsigned short* kp = Kb + (size_t)m * 128;
            short8 kv0 = *(const short8*)(kp);
            short8 kv1 = *(const short8*)(kp + 8);
            short8 kv2 = *(const short8*)(kp + 16);
            short8 kv3 = *(const short8*)(kp + 24);
            float s = 0.f;
            #pragma unroll
            for (int e = 0; e < 8; ++e) {
                int k0 = e, k1 = 8 + e, k2 = 16 + e, k3 = 24 + e;
                s += qv[k0 >> 2][k0 & 3] * b2f((unsigned short)kv0[e]);
                s += qv[k1 >> 2][k1 & 3] * b2f((unsigned short)kv1[e]);
                s += qv[k2 >> 2][k2 & 3] * b2f((unsigned short)kv2[e]);
                s += qv[k3 >> 2][k3 & 3] * b2f((unsigned short)kv3[e]);
            }
            if (act) {
                wls[wv][j] = s;
                smax = fmaxf(smax, s);
            }
        }
        #pragma unroll
        for (int d = 1; d < 64; d <<= 1) smax = fmaxf(smax, __shfl_xor(smax, d, 64));

        // pass B: exp, sum, reweight by tm
        float zs = 0.f;
        for (int it = 0; it < itmax; ++it) {
            int j = it * 64 + lane;
            if (j < nnz) {
                float e = __expf(wls[wv][j] - smax);
                zs += e;
                wls[wv][j] = e * tmw[j];
            }
        }
        #pragma unroll
        for (int d = 1; d < 64; d <<= 1) zs += __shfl_xor(zs, d, 64);
        float inv_z = (zs > 0.f) ? (1.0f / zs) : 0.f;

        // pass C: PV; halves split j, lanes 0..31 = k (coalesced 64B V loads)
        float acc = 0.f;
        for (int j = half; j < nnz; j += 2) {
            float w = wls[wv][j];
            int m = midx[j];
            acc += w * b2f(Vb[(size_t)m * 128 + k31]);
        }
        acc += __shfl_down(acc, 32, 64);
        if (lane < 32) {
            att_ws[((size_t)bp * 512 + n) * 384 + toff + h * 32 + k31] = f2b(acc * inv_z);
        }
    }
}

// ---------------- K3: out-projection (MFMA) + residual + LayerNorm ----------------
// grid (bp=32, mt=8); LDS = As(16KB) + Ws(32KB) = 48KB. OUTPUT = F32.
__global__ __launch_bounds__(256) void k_oproj(
    const unsigned short* __restrict__ att_ws,   // [32][512][384] bf16
    const float* __restrict__ Wo,                // [128][384] f32
    const float* __restrict__ X,                 // [32][512][128] f32 (residual)
    const float* __restrict__ gamma,
    const float* __restrict__ beta,
    float* __restrict__ out,                     // [32][512][128] f32
    float sentinel)
{
    int bp = blockIdx.x;
    int mt = blockIdx.y;
    __shared__ unsigned short As[64 * 128];
    __shared__ unsigned short Ws[128 * 128];
    int tid = threadIdx.x, lane = tid & 63, wv = tid >> 6;
    int l15 = lane & 15, quad = lane >> 4;

    floatx4 acc[8];
    for (int ct = 0; ct < 8; ++ct) acc[ct] = (floatx4){0.f, 0.f, 0.f, 0.f};

    size_t rowbase = (size_t)bp * 512 + mt * 64;

    for (int kc = 0; kc < 3; ++kc) {
        __syncthreads();
        for (int i = 0; i < 4; ++i) {            // As: 64x128 (bf16 copy)
            int flat = i * 256 + tid;
            int row = flat >> 4, colg = (flat & 15) * 8;
            *(short8*)&As[row * 128 + colg] =
                *(const short8*)&att_ws[(rowbase + row) * 384 + kc * 128 + colg];
        }
        for (int i = 0; i < 8; ++i) {            // Ws: 128x128 chunk of Wo (f32 -> bf16)
            int flat = i * 256 + tid;
            int row = flat >> 4, colg = (flat & 15) * 8;
            *(short8*)&Ws[row * 128 + colg] = cvt8(&Wo[(size_t)row * 384 + kc * 128 + colg]);
        }
        __syncthreads();
        for (int ct = 0; ct < 8; ++ct) {
            for (int kk = 0; kk < 4; ++kk) {
                short8 a = *(const short8*)&As[(wv * 16 + l15) * 128 + kk * 32 + quad * 8];
                short8 b = *(const short8*)&Ws[(ct * 16 + l15) * 128 + kk * 32 + quad * 8];
                acc[ct] = __builtin_amdgcn_mfma_f32_16x16x32_bf16(a, b, acc[ct], 0, 0, 0);
            }
        }
    }

    for (int i = 0; i < 4; ++i) {
        int lrow = wv * 16 + quad * 4 + i;
        size_t grow = rowbase + lrow;
        float vals[8];
        float s = 0.f, sq = 0.f;
        for (int ct = 0; ct < 8; ++ct) {
            int col = ct * 16 + l15;
            float v = acc[ct][i] + X[grow * 128 + col];
            vals[ct] = v;
            s += v; sq += v * v;
        }
        for (int d = 1; d < 16; d <<= 1) {
            s  += __shfl_xor(s, d, 64);
            sq += __shfl_xor(sq, d, 64);
        }
        float mu = s * (1.0f / 128.0f);
        float var = sq * (1.0f / 128.0f) - mu * mu;
        float rs = rsqrtf(var + 1e-5f);
        for (int ct = 0; ct < 8; ++ct) {
            int col = ct * 16 + l15;
            float g = gamma[col], bb = beta[col];
            out[grow * 128 + col] = (vals[ct] - mu) * rs * g + bb + sentinel;
        }
    }
}

// ---------------- launcher ----------------
extern "C" void kernel_launch(void* const* d_in, const int* in_sizes, int n_in,
                              void* d_out, int out_size, void* d_ws, size_t ws_size,
                              hipStream_t stream) {
    const float* X     = (const float*)d_in[0];
    const float* TM    = (const float*)d_in[2];
    const float* Wq    = (const float*)d_in[3];
    const float* Wk    = (const float*)d_in[4];
    const float* Wv    = (const float*)d_in[5];
    const float* Wo    = (const float*)d_in[6];
    const float* gamma = (const float*)d_in[7];
    const float* beta  = (const float*)d_in[8];
    float* out = (float*)d_out;

    char* ws = (char*)d_ws;
    unsigned short* q_ws   = (unsigned short*)(ws);
    unsigned short* k_ws   = (unsigned short*)(ws + 4194304);
    unsigned short* v_ws   = (unsigned short*)(ws + 8388608);
    unsigned short* att_ws = (unsigned short*)(ws + 12582912);  // [32][512][384]

    const int tsel[3] = {0, 1, 3};
    for (int t = 0; t < 3; ++t) {
        k_qkv<<<dim3(32, 4), 256, 0, stream>>>(
            X, Wq + (size_t)t * 16384, Wk + (size_t)t * 16384, Wv + (size_t)t * 16384,
            q_ws, k_ws, v_ws);
        k_attn<<<dim3(512), 512, 0, stream>>>(
            q_ws, k_ws, v_ws, TM + (size_t)tsel[t] * 512 * 512, att_ws, t * 128);
    }
    float sentinel = (ws_size < WS_NEED) ? 1024.0f : 0.0f;
    k_oproj<<<dim3(32, 8), 256, 0, stream>>>(att_ws, Wo, X, gamma, beta, out, sentinel);
}

// Round 7
// 426.153 us; speedup vs baseline: 1.7863x; 1.1800x over previous
//
#include <hip/hip_runtime.h>

// ---------------- problem constants ----------------
// B*P=32, N=512, D=128, H=4, DK=32, T=3 (tm {0,1,3}; tsel[t] = t + (t>>1))
// Inputs f32, OUTPUT f32. LDS < 64KB. R6: k_attn latency-bound at occupancy
// 34% (512 blocks = 2/CU). R7: 4x grid split (block per (n,g), 8 bp each) and,
// when ws_size >= 50.3MB, fuse the t-loop into 3 total dispatches.

typedef __attribute__((ext_vector_type(8))) short  short8;
typedef __attribute__((ext_vector_type(4))) float  floatx4;

#define WS_SMALL 25165824ull   // fallback layout: q+k+v (12.6MB) + att (12.6MB)
#define WS_BIG   50331648ull   // fused layout: 3x q/k/v (37.7MB) + att (12.6MB)

__device__ __forceinline__ float b2f(unsigned short u) {
    union { unsigned int i; float f; } v; v.i = ((unsigned int)u) << 16; return v.f;
}
__device__ __forceinline__ unsigned short f2b(float f) {
    union { float f; unsigned int i; } v; v.f = f;
    unsigned int x = v.i;
    return (unsigned short)((x + 0x7fffu + ((x >> 16) & 1u)) >> 16);
}
__device__ __forceinline__ short8 cvt8(const float* p) {
    floatx4 a = *(const floatx4*)p;
    floatx4 b = *(const floatx4*)(p + 4);
    short8 r;
    r[0] = (short)f2b(a[0]); r[1] = (short)f2b(a[1]);
    r[2] = (short)f2b(a[2]); r[3] = (short)f2b(a[3]);
    r[4] = (short)f2b(b[0]); r[5] = (short)f2b(b[1]);
    r[6] = (short)f2b(b[2]); r[7] = (short)f2b(b[3]);
    return r;
}

// ---------------- K1: QKV projection (MFMA bf16) ----------------
// grid (bp=32, mt=4, tz); z picks t via strides (0 strides + offset ptrs = per-t)
__global__ __launch_bounds__(256) void k_qkv(
    const float* __restrict__ X,             // [32][512][128] f32
    const float* __restrict__ Wq,            // [128][128] f32 (+ tz*wstride)
    const float* __restrict__ Wk,
    const float* __restrict__ Wv,
    unsigned short* __restrict__ q_ws,       // bf16 (+ tz*ostride)
    unsigned short* __restrict__ k_ws,
    unsigned short* __restrict__ v_ws,
    int wstride, int ostride)
{
    int bp = blockIdx.x;
    int mt = blockIdx.y;
    int tz = blockIdx.z;
    __shared__ unsigned short Xs[128 * 128];     // 32 KB
    int tid = threadIdx.x;
    int lane = tid & 63, wv = tid >> 6;
    int l15 = lane & 15, quad = lane >> 4;

    const float* Xbase = X + ((size_t)bp * 512 + mt * 128) * 128;
    for (int i = 0; i < 8; ++i) {
        int e = (i * 256 + tid) * 8;
        *(short8*)&Xs[e] = cvt8(&Xbase[e]);
    }
    __syncthreads();

    size_t woff = (size_t)tz * wstride;
    size_t ooff = (size_t)tz * ostride;
    const float* Wsel[3] = { Wq + woff, Wk + woff, Wv + woff };
    unsigned short* Osel[3] = { q_ws + ooff, k_ws + ooff, v_ws + ooff };

    for (int qkv = 0; qkv < 3; ++qkv) {
        const float* Wb = Wsel[qkv];
        unsigned short* Ob = Osel[qkv] + ((size_t)bp * 512 + mt * 128) * 128;
        for (int ct = 0; ct < 8; ++ct) {
            short8 bfr[4];
            for (int kk = 0; kk < 4; ++kk)
                bfr[kk] = cvt8(&Wb[(size_t)(ct * 16 + l15) * 128 + kk * 32 + quad * 8]);
            floatx4 acc0 = {0.f, 0.f, 0.f, 0.f};
            floatx4 acc1 = {0.f, 0.f, 0.f, 0.f};
            int rt0 = wv * 2, rt1 = wv * 2 + 1;
            for (int kk = 0; kk < 4; ++kk) {
                short8 a0 = *(const short8*)&Xs[(rt0 * 16 + l15) * 128 + kk * 32 + quad * 8];
                short8 a1 = *(const short8*)&Xs[(rt1 * 16 + l15) * 128 + kk * 32 + quad * 8];
                acc0 = __builtin_amdgcn_mfma_f32_16x16x32_bf16(a0, bfr[kk], acc0, 0, 0, 0);
                acc1 = __builtin_amdgcn_mfma_f32_16x16x32_bf16(a1, bfr[kk], acc1, 0, 0, 0);
            }
            int col = ct * 16 + l15;
            for (int i = 0; i < 4; ++i) {
                Ob[(size_t)(rt0 * 16 + quad * 4 + i) * 128 + col] = f2b(acc0[i]);
                Ob[(size_t)(rt1 * 16 + quad * 4 + i) * 128 + col] = f2b(acc1[i]);
            }
        }
    }
}

// ---------------- K2: sparse masked attention (block per (n, g, tz)) ----------
// block 512 thr (8 waves); block handles bp in [g*8, g*8+8), all 4 heads.
// Wave wv: h = wv&3, bp = g*8 + ii*2 + (wv>>2), ii=0..3.
// tm matrix for tz: TM + (tz + (tz>>1))*262144 (tsel trick). Per-t launches
// pass pre-offset tm and tz=0.
// LDS: Qs 4KB + midx 1KB + tmw 2KB + wls 16KB + segcnt = ~23.2KB.
__global__ __launch_bounds__(512) void k_attn(
    const unsigned short* __restrict__ q_ws,   // bf16 (+ tz*qkv_stride)
    const unsigned short* __restrict__ k_ws,
    const unsigned short* __restrict__ v_ws,
    const float* __restrict__ tm_base,         // fused: TM base; fallback: pre-offset row0
    unsigned short* __restrict__ att_ws,       // [32][512][384] bf16
    int qkv_stride, int toff)                  // fused: (2097152, 0); fallback: (0, t*128)
{
    int n = blockIdx.x;
    int g = blockIdx.y;
    int tz = blockIdx.z;
    __shared__ float          Qs[8][128];      // f32, pre-scaled by 1/sqrt(dk)
    __shared__ unsigned short midx[512];
    __shared__ float          tmw[512];
    __shared__ float          wls[8][512];
    __shared__ int            segcnt[8];

    int tid = threadIdx.x, lane = tid & 63, wv = tid >> 6;   // wv 0..7
    const float inv_sqrt_dk = 0.17677669529663687f;
    size_t qoff = (size_t)tz * qkv_stride;

    // --- compaction phase 1: wave wv ballots segment wv of tm row n
    const float* tmrow = tm_base + (size_t)(tz + (tz >> 1)) * 262144 + (size_t)n * 512;
    float tv = tmrow[wv * 64 + lane];
    unsigned long long bmask = __ballot(tv != 0.0f);
    if (lane == 0) segcnt[wv] = __popcll(bmask);

    // --- stage Qs: 8 bp rows (g*8..g*8+7), 2 elems per thread, pre-scaled f32
    {
        int e = tid * 2;
        int bpl = e >> 7, d = e & 127;
        unsigned int u = *(const unsigned int*)&q_ws[qoff +
            ((size_t)(g * 8 + bpl) * 512 + n) * 128 + d];
        Qs[bpl][d]     = b2f((unsigned short)(u & 0xffff)) * inv_sqrt_dk;
        Qs[bpl][d + 1] = b2f((unsigned short)(u >> 16))    * inv_sqrt_dk;
    }
    __syncthreads();

    // --- compaction phase 2: prefix offsets, scatter midx/tmw
    int off = 0, nnz = 0;
    #pragma unroll
    for (int s = 0; s < 8; ++s) {
        int c = segcnt[s];
        if (s < wv) off += c;
        nnz += c;
    }
    if (tv != 0.0f) {
        int pos = off + __popcll(bmask & ((1ull << lane) - 1ull));
        midx[pos] = (unsigned short)(wv * 64 + lane);
        tmw[pos] = tv;
    }
    __syncthreads();

    int itmax = (nnz + 63) >> 6;
    int h = wv & 3;
    int k31 = lane & 31, half = lane >> 5;

    for (int ii = 0; ii < 4; ++ii) {
        int bpl = ii * 2 + (wv >> 2);          // 0..7
        int bp = g * 8 + bpl;
        const unsigned short* Kb = k_ws + qoff + (size_t)bp * 512 * 128 + h * 32;
        const unsigned short* Vb = v_ws + qoff + (size_t)bp * 512 * 128 + h * 32;

        // q row into registers (LDS broadcast reads, conflict-free)
        floatx4 qv[8];
        #pragma unroll
        for (int c = 0; c < 8; ++c) qv[c] = *(const floatx4*)&Qs[bpl][h * 32 + c * 4];

        // pass A: scores for compacted columns (random 64B K-row global gathers)
        float smax = -3.0e38f;
        for (int it = 0; it < itmax; ++it) {
            int j = it * 64 + lane;
            bool act = j < nnz;
            int m = act ? (int)midx[j] : (int)midx[0];
            const unsigned short* kp = Kb + (size_t)m * 128;
            short8 kv0 = *(const short8*)(kp);
            short8 kv1 = *(const short8*)(kp + 8);
            short8 kv2 = *(const short8*)(kp + 16);
            short8 kv3 = *(const short8*)(kp + 24);
            float s = 0.f;
            #pragma unroll
            for (int e = 0; e < 8; ++e) {
                s += qv[e >> 2][e & 3]            * b2f((unsigned short)kv0[e]);
                s += qv[(8 + e) >> 2][(8 + e) & 3] * b2f((unsigned short)kv1[e]);
                s += qv[(16 + e) >> 2][e & 3]      * b2f((unsigned short)kv2[e]);
                s += qv[(24 + e) >> 2][e & 3]      * b2f((unsigned short)kv3[e]);
            }
            if (act) {
                wls[wv][j] = s;
                smax = fmaxf(smax, s);
            }
        }
        #pragma unroll
        for (int d = 1; d < 64; d <<= 1) smax = fmaxf(smax, __shfl_xor(smax, d, 64));

        // pass B: exp, sum, reweight by tm
        float zs = 0.f;
        for (int it = 0; it < itmax; ++it) {
            int j = it * 64 + lane;
            if (j < nnz) {
                float e = __expf(wls[wv][j] - smax);
                zs += e;
                wls[wv][j] = e * tmw[j];
            }
        }
        #pragma unroll
        for (int d = 1; d < 64; d <<= 1) zs += __shfl_xor(zs, d, 64);
        float inv_z = (zs > 0.f) ? (1.0f / zs) : 0.f;

        // pass C: PV; halves split j, lanes 0..31 = k (coalesced 64B V loads)
        float acc = 0.f;
        for (int j = half; j < nnz; j += 2) {
            float w = wls[wv][j];
            int m = midx[j];
            acc += w * b2f(Vb[(size_t)m * 128 + k31]);
        }
        acc += __shfl_down(acc, 32, 64);
        if (lane < 32) {
            att_ws[((size_t)bp * 512 + n) * 384 + tz * 128 + toff + h * 32 + k31] =
                f2b(acc * inv_z);
        }
    }
}

// ---------------- K3: out-projection (MFMA) + residual + LayerNorm ----------------
__global__ __launch_bounds__(256) void k_oproj(
    const unsigned short* __restrict__ att_ws,   // [32][512][384] bf16
    const float* __restrict__ Wo,                // [128][384] f32
    const float* __restrict__ X,                 // [32][512][128] f32 (residual)
    const float* __restrict__ gamma,
    const float* __restrict__ beta,
    float* __restrict__ out,                     // [32][512][128] f32
    float sentinel)
{
    int bp = blockIdx.x;
    int mt = blockIdx.y;
    __shared__ unsigned short As[64 * 128];
    __shared__ unsigned short Ws[128 * 128];
    int tid = threadIdx.x, lane = tid & 63, wv = tid >> 6;
    int l15 = lane & 15, quad = lane >> 4;

    floatx4 acc[8];
    for (int ct = 0; ct < 8; ++ct) acc[ct] = (floatx4){0.f, 0.f, 0.f, 0.f};

    size_t rowbase = (size_t)bp * 512 + mt * 64;

    for (int kc = 0; kc < 3; ++kc) {
        __syncthreads();
        for (int i = 0; i < 4; ++i) {
            int flat = i * 256 + tid;
            int row = flat >> 4, colg = (flat & 15) * 8;
            *(short8*)&As[row * 128 + colg] =
                *(const short8*)&att_ws[(rowbase + row) * 384 + kc * 128 + colg];
        }
        for (int i = 0; i < 8; ++i) {
            int flat = i * 256 + tid;
            int row = flat >> 4, colg = (flat & 15) * 8;
            *(short8*)&Ws[row * 128 + colg] = cvt8(&Wo[(size_t)row * 384 + kc * 128 + colg]);
        }
        __syncthreads();
        for (int ct = 0; ct < 8; ++ct) {
            for (int kk = 0; kk < 4; ++kk) {
                short8 a = *(const short8*)&As[(wv * 16 + l15) * 128 + kk * 32 + quad * 8];
                short8 b = *(const short8*)&Ws[(ct * 16 + l15) * 128 + kk * 32 + quad * 8];
                acc[ct] = __builtin_amdgcn_mfma_f32_16x16x32_bf16(a, b, acc[ct], 0, 0, 0);
            }
        }
    }

    for (int i = 0; i < 4; ++i) {
        int lrow = wv * 16 + quad * 4 + i;
        size_t grow = rowbase + lrow;
        float vals[8];
        float s = 0.f, sq = 0.f;
        for (int ct = 0; ct < 8; ++ct) {
            int col = ct * 16 + l15;
            float v = acc[ct][i] + X[grow * 128 + col];
            vals[ct] = v;
            s += v; sq += v * v;
        }
        for (int d = 1; d < 16; d <<= 1) {
            s  += __shfl_xor(s, d, 64);
            sq += __shfl_xor(sq, d, 64);
        }
        float mu = s * (1.0f / 128.0f);
        float var = sq * (1.0f / 128.0f) - mu * mu;
        float rs = rsqrtf(var + 1e-5f);
        for (int ct = 0; ct < 8; ++ct) {
            int col = ct * 16 + l15;
            float g = gamma[col], bb = beta[col];
            out[grow * 128 + col] = (vals[ct] - mu) * rs * g + bb + sentinel;
        }
    }
}

// ---------------- launcher ----------------
extern "C" void kernel_launch(void* const* d_in, const int* in_sizes, int n_in,
                              void* d_out, int out_size, void* d_ws, size_t ws_size,
                              hipStream_t stream) {
    const float* X     = (const float*)d_in[0];
    const float* TM    = (const float*)d_in[2];
    const float* Wq    = (const float*)d_in[3];
    const float* Wk    = (const float*)d_in[4];
    const float* Wv    = (const float*)d_in[5];
    const float* Wo    = (const float*)d_in[6];
    const float* gamma = (const float*)d_in[7];
    const float* beta  = (const float*)d_in[8];
    float* out = (float*)d_out;

    char* ws = (char*)d_ws;
    const size_t QKV1 = 2097152;             // elems per t per tensor
    const size_t QKV1B = QKV1 * 2;           // 4 MB

    if (ws_size >= WS_BIG) {
        // fused path: 3 dispatches total
        unsigned short* q3  = (unsigned short*)(ws);
        unsigned short* k3  = (unsigned short*)(ws + 3 * QKV1B);
        unsigned short* v3  = (unsigned short*)(ws + 6 * QKV1B);
        unsigned short* att = (unsigned short*)(ws + 9 * QKV1B);
        k_qkv<<<dim3(32, 4, 3), 256, 0, stream>>>(
            X, Wq, Wk, Wv, q3, k3, v3, 16384, (int)QKV1);
        k_attn<<<dim3(512, 4, 3), 512, 0, stream>>>(
            q3, k3, v3, TM, att, (int)QKV1, 0);
        k_oproj<<<dim3(32, 8), 256, 0, stream>>>(att, Wo, X, gamma, beta, out, 0.0f);
    } else {
        // fallback: per-t loop (proven R6 structure + 4x grid split)
        unsigned short* q_ws   = (unsigned short*)(ws);
        unsigned short* k_ws   = (unsigned short*)(ws + QKV1B);
        unsigned short* v_ws   = (unsigned short*)(ws + 2 * QKV1B);
        unsigned short* att_ws = (unsigned short*)(ws + 3 * QKV1B);
        const int tsel[3] = {0, 1, 3};
        for (int t = 0; t < 3; ++t) {
            k_qkv<<<dim3(32, 4, 1), 256, 0, stream>>>(
                X, Wq + (size_t)t * 16384, Wk + (size_t)t * 16384, Wv + (size_t)t * 16384,
                q_ws, k_ws, v_ws, 0, 0);
            k_attn<<<dim3(512, 4, 1), 512, 0, stream>>>(
                q_ws, k_ws, v_ws, TM + (size_t)tsel[t] * 262144, att_ws, 0, t * 128);
        }
        float sentinel = (ws_size < WS_SMALL) ? 1024.0f : 0.0f;
        k_oproj<<<dim3(32, 8), 256, 0, stream>>>(att_ws, Wo, X, gamma, beta, out, sentinel);
    }
}

// Round 8
// 217.396 us; speedup vs baseline: 3.5016x; 1.9603x over previous
//
#include <hip/hip_runtime.h>

// ---------------- problem constants ----------------
// B*P=32, N=512, D=128, H=4, DK=32, T=3 (tm {0,1,3}; tsel(t)=t+(t>>1))
// Inputs f32, OUTPUT f32. ws >= 50.3MB confirmed (fused path ran in R7).
// R7 post-mortem: sparse k_attn is VALU-bound-at-33%-busy (~600 VALU/instance
// of cvt/extract/addr work, MfmaUtil 0). Dense attention is only 12.9 GF ->
// ~6us MFMA floor. R8: k_attn rewritten as dense MFMA flash-style:
//   S = mfma(Qfrag, Kfrag) per 16x16 tile, mask+exp+tm in C-layout regs
//   (no max-subtraction: |s|<~7 safe; Z>0 via unit diagonal), P through
//   per-wave LDS scratch (barrier-free) into PV mfma with V transposed in LDS.

typedef __attribute__((ext_vector_type(8))) short  short8;
typedef __attribute__((ext_vector_type(4))) float  floatx4;

#define WS_SMALL 25165824ull
#define WS_BIG   50331648ull

__device__ __forceinline__ float b2f(unsigned short u) {
    union { unsigned int i; float f; } v; v.i = ((unsigned int)u) << 16; return v.f;
}
__device__ __forceinline__ unsigned short f2b(float f) {
    union { float f; unsigned int i; } v; v.f = f;
    unsigned int x = v.i;
    return (unsigned short)((x + 0x7fffu + ((x >> 16) & 1u)) >> 16);
}
__device__ __forceinline__ short8 cvt8(const float* p) {
    floatx4 a = *(const floatx4*)p;
    floatx4 b = *(const floatx4*)(p + 4);
    short8 r;
    r[0] = (short)f2b(a[0]); r[1] = (short)f2b(a[1]);
    r[2] = (short)f2b(a[2]); r[3] = (short)f2b(a[3]);
    r[4] = (short)f2b(b[0]); r[5] = (short)f2b(b[1]);
    r[6] = (short)f2b(b[2]); r[7] = (short)f2b(b[3]);
    return r;
}

// ---------------- K1: QKV projection (MFMA bf16) ----------------
// grid (bp=32, mt=4, tz). Q output pre-scaled by 1/sqrt(DK).
__global__ __launch_bounds__(256) void k_qkv(
    const float* __restrict__ X,             // [32][512][128] f32
    const float* __restrict__ Wq,            // [128][128] f32 (+ tz*wstride)
    const float* __restrict__ Wk,
    const float* __restrict__ Wv,
    unsigned short* __restrict__ q_ws,       // bf16 (+ tz*ostride)
    unsigned short* __restrict__ k_ws,
    unsigned short* __restrict__ v_ws,
    int wstride, int ostride)
{
    int bp = blockIdx.x;
    int mt = blockIdx.y;
    int tz = blockIdx.z;
    __shared__ unsigned short Xs[128 * 128];     // 32 KB
    int tid = threadIdx.x;
    int lane = tid & 63, wv = tid >> 6;
    int l15 = lane & 15, quad = lane >> 4;

    const float* Xbase = X + ((size_t)bp * 512 + mt * 128) * 128;
    for (int i = 0; i < 8; ++i) {
        int e = (i * 256 + tid) * 8;
        *(short8*)&Xs[e] = cvt8(&Xbase[e]);
    }
    __syncthreads();

    size_t woff = (size_t)tz * wstride;
    size_t ooff = (size_t)tz * ostride;
    const float* Wsel[3] = { Wq + woff, Wk + woff, Wv + woff };
    unsigned short* Osel[3] = { q_ws + ooff, k_ws + ooff, v_ws + ooff };

    for (int qkv = 0; qkv < 3; ++qkv) {
        const float* Wb = Wsel[qkv];
        unsigned short* Ob = Osel[qkv] + ((size_t)bp * 512 + mt * 128) * 128;
        float sc = (qkv == 0) ? 0.17677669529663687f : 1.0f;  // fold 1/sqrt(32) into Q
        for (int ct = 0; ct < 8; ++ct) {
            short8 bfr[4];
            for (int kk = 0; kk < 4; ++kk)
                bfr[kk] = cvt8(&Wb[(size_t)(ct * 16 + l15) * 128 + kk * 32 + quad * 8]);
            floatx4 acc0 = {0.f, 0.f, 0.f, 0.f};
            floatx4 acc1 = {0.f, 0.f, 0.f, 0.f};
            int rt0 = wv * 2, rt1 = wv * 2 + 1;
            for (int kk = 0; kk < 4; ++kk) {
                short8 a0 = *(const short8*)&Xs[(rt0 * 16 + l15) * 128 + kk * 32 + quad * 8];
                short8 a1 = *(const short8*)&Xs[(rt1 * 16 + l15) * 128 + kk * 32 + quad * 8];
                acc0 = __builtin_amdgcn_mfma_f32_16x16x32_bf16(a0, bfr[kk], acc0, 0, 0, 0);
                acc1 = __builtin_amdgcn_mfma_f32_16x16x32_bf16(a1, bfr[kk], acc1, 0, 0, 0);
            }
            int col = ct * 16 + l15;
            for (int i = 0; i < 4; ++i) {
                Ob[(size_t)(rt0 * 16 + quad * 4 + i) * 128 + col] = f2b(acc0[i] * sc);
                Ob[(size_t)(rt1 * 16 + quad * 4 + i) * 128 + col] = f2b(acc1[i] * sc);
            }
        }
    }
}

// ---------------- K2: dense MFMA masked attention ----------------
// grid (nc=4, bp=32, z: t*4+h). Block 512 thr = 8 waves; wave = 16-row Q strip.
// Per m-chunk of 64: 4 S-tiles via MFMA, mask/exp/tm in C-layout, P -> per-wave
// LDS scratch (barrier-free), PV via MFMA with Vt (V transposed in LDS).
// No max-subtraction (|s| <= ~7 -> exp safe; Z > 0 via tm unit diagonal).
// LDS: Vt 32x516x2 = 33,024 + Ps 8x16x72x2 = 18,432 -> 51.5 KB (3 blocks/CU).
__global__ __launch_bounds__(512) void k_attn(
    const unsigned short* __restrict__ q_ws,   // bf16, pre-scaled (+ t*qkv_stride)
    const unsigned short* __restrict__ k_ws,
    const unsigned short* __restrict__ v_ws,
    const float* __restrict__ tm,              // fused: TM base; fallback: pre-offset
    unsigned short* __restrict__ att_ws,       // [32][512][384] bf16
    int qkv_stride, int toff0)
{
    int nc = blockIdx.x;
    int bp = blockIdx.y;
    int z  = blockIdx.z;
    int t = z >> 2, h = z & 3;
    size_t qoff = (size_t)t * (size_t)qkv_stride;
    const float* tmt = tm + (size_t)(t + (t >> 1)) * 262144;
    int toff = toff0 + t * 128;

    __shared__ unsigned short Vt[32][516];     // V^T slice (pad 4: banks spread)
    __shared__ unsigned short Ps[8][16][72];   // per-wave P scratch (pad 8)

    int tid = threadIdx.x, lane = tid & 63, wv = tid >> 6;
    int l15 = lane & 15, quad = lane >> 4;

    // stage V transposed: thread m=tid reads its 32-elem head slice, scatters
    {
        const unsigned short* vp = v_ws + qoff + ((size_t)bp * 512 + tid) * 128 + h * 32;
        short8 a = *(const short8*)vp;
        short8 b = *(const short8*)(vp + 8);
        short8 c = *(const short8*)(vp + 16);
        short8 d = *(const short8*)(vp + 24);
        #pragma unroll
        for (int j = 0; j < 8; ++j) {
            Vt[j][tid]      = (unsigned short)a[j];
            Vt[8 + j][tid]  = (unsigned short)b[j];
            Vt[16 + j][tid] = (unsigned short)c[j];
            Vt[24 + j][tid] = (unsigned short)d[j];
        }
    }
    // Q A-frag for this wave's 16-row strip (held in regs for whole kernel)
    int n0 = nc * 128 + wv * 16;
    short8 qf = *(const short8*)&q_ws[qoff +
        ((size_t)bp * 512 + n0 + l15) * 128 + h * 32 + quad * 8];
    __syncthreads();

    const unsigned short* Kb = k_ws + qoff + (size_t)bp * 512 * 128 + h * 32;
    floatx4 O0 = {0.f, 0.f, 0.f, 0.f};
    floatx4 O1 = {0.f, 0.f, 0.f, 0.f};
    float za[4] = {0.f, 0.f, 0.f, 0.f};
    const floatx4 zero4 = {0.f, 0.f, 0.f, 0.f};

    for (int c = 0; c < 8; ++c) {
        int mb = c * 64;
        // 4 S-tiles: B-frags = K rows direct from global (L1-shared across waves)
        short8 kf0 = *(const short8*)&Kb[(size_t)(mb +  0 + l15) * 128 + quad * 8];
        short8 kf1 = *(const short8*)&Kb[(size_t)(mb + 16 + l15) * 128 + quad * 8];
        short8 kf2 = *(const short8*)&Kb[(size_t)(mb + 32 + l15) * 128 + quad * 8];
        short8 kf3 = *(const short8*)&Kb[(size_t)(mb + 48 + l15) * 128 + quad * 8];
        floatx4 S[4];
        S[0] = __builtin_amdgcn_mfma_f32_16x16x32_bf16(qf, kf0, zero4, 0, 0, 0);
        S[1] = __builtin_amdgcn_mfma_f32_16x16x32_bf16(qf, kf1, zero4, 0, 0, 0);
        S[2] = __builtin_amdgcn_mfma_f32_16x16x32_bf16(qf, kf2, zero4, 0, 0, 0);
        S[3] = __builtin_amdgcn_mfma_f32_16x16x32_bf16(qf, kf3, zero4, 0, 0, 0);

        // mask + exp + tm reweight; write P tile to per-wave scratch
        #pragma unroll
        for (int ti = 0; ti < 4; ++ti) {
            int m = mb + ti * 16 + l15;
            #pragma unroll
            for (int i = 0; i < 4; ++i) {
                float tmv = tmt[(size_t)(n0 + quad * 4 + i) * 512 + m];
                float e = __expf(S[ti][i]);              // q pre-scaled; no max-sub
                bool on = (tmv != 0.0f);
                za[i] += on ? e : 0.0f;                  // Z sums exp over mask only
                float w = on ? e * tmv : 0.0f;           // P = alpha_unnorm * tm
                Ps[wv][quad * 4 + i][ti * 16 + l15] = f2b(w);
            }
        }
        // PV: A = P (rows n), B = Vt (rows k); accumulate O[16n x 32k]
        #pragma unroll
        for (int kc = 0; kc < 2; ++kc) {
            short8 pa  = *(const short8*)&Ps[wv][l15][kc * 32 + quad * 8];
            short8 vb0 = *(const short8*)&Vt[l15][mb + kc * 32 + quad * 8];
            short8 vb1 = *(const short8*)&Vt[16 + l15][mb + kc * 32 + quad * 8];
            O0 = __builtin_amdgcn_mfma_f32_16x16x32_bf16(pa, vb0, O0, 0, 0, 0);
            O1 = __builtin_amdgcn_mfma_f32_16x16x32_bf16(pa, vb1, O1, 0, 0, 0);
        }
    }

    // reduce Z over the 16 lanes of each quad (rows quad*4+i match O rows)
    #pragma unroll
    for (int d = 1; d < 16; d <<= 1) {
        #pragma unroll
        for (int i = 0; i < 4; ++i) za[i] += __shfl_xor(za[i], d, 64);
    }
    #pragma unroll
    for (int i = 0; i < 4; ++i) {
        float rz = 1.0f / za[i];                         // Z > 0 (unit diagonal)
        size_t row = (size_t)bp * 512 + n0 + quad * 4 + i;
        att_ws[row * 384 + toff + h * 32 + l15]      = f2b(O0[i] * rz);
        att_ws[row * 384 + toff + h * 32 + 16 + l15] = f2b(O1[i] * rz);
    }
}

// ---------------- K3: out-projection (MFMA) + residual + LayerNorm ----------------
__global__ __launch_bounds__(256) void k_oproj(
    const unsigned short* __restrict__ att_ws,   // [32][512][384] bf16
    const float* __restrict__ Wo,                // [128][384] f32
    const float* __restrict__ X,                 // [32][512][128] f32 (residual)
    const float* __restrict__ gamma,
    const float* __restrict__ beta,
    float* __restrict__ out)                     // [32][512][128] f32
{
    int bp = blockIdx.x;
    int mt = blockIdx.y;
    __shared__ unsigned short As[64 * 128];
    __shared__ unsigned short Ws[128 * 128];
    int tid = threadIdx.x, lane = tid & 63, wv = tid >> 6;
    int l15 = lane & 15, quad = lane >> 4;

    floatx4 acc[8];
    for (int ct = 0; ct < 8; ++ct) acc[ct] = (floatx4){0.f, 0.f, 0.f, 0.f};

    size_t rowbase = (size_t)bp * 512 + mt * 64;

    for (int kc = 0; kc < 3; ++kc) {
        __syncthreads();
        for (int i = 0; i < 4; ++i) {
            int flat = i * 256 + tid;
            int row = flat >> 4, colg = (flat & 15) * 8;
            *(short8*)&As[row * 128 + colg] =
                *(const short8*)&att_ws[(rowbase + row) * 384 + kc * 128 + colg];
        }
        for (int i = 0; i < 8; ++i) {
            int flat = i * 256 + tid;
            int row = flat >> 4, colg = (flat & 15) * 8;
            *(short8*)&Ws[row * 128 + colg] = cvt8(&Wo[(size_t)row * 384 + kc * 128 + colg]);
        }
        __syncthreads();
        for (int ct = 0; ct < 8; ++ct) {
            for (int kk = 0; kk < 4; ++kk) {
                short8 a = *(const short8*)&As[(wv * 16 + l15) * 128 + kk * 32 + quad * 8];
                short8 b = *(const short8*)&Ws[(ct * 16 + l15) * 128 + kk * 32 + quad * 8];
                acc[ct] = __builtin_amdgcn_mfma_f32_16x16x32_bf16(a, b, acc[ct], 0, 0, 0);
            }
        }
    }

    for (int i = 0; i < 4; ++i) {
        int lrow = wv * 16 + quad * 4 + i;
        size_t grow = rowbase + lrow;
        float vals[8];
        float s = 0.f, sq = 0.f;
        for (int ct = 0; ct < 8; ++ct) {
            int col = ct * 16 + l15;
            float v = acc[ct][i] + X[grow * 128 + col];
            vals[ct] = v;
            s += v; sq += v * v;
        }
        for (int d = 1; d < 16; d <<= 1) {
            s  += __shfl_xor(s, d, 64);
            sq += __shfl_xor(sq, d, 64);
        }
        float mu = s * (1.0f / 128.0f);
        float var = sq * (1.0f / 128.0f) - mu * mu;
        float rs = rsqrtf(var + 1e-5f);
        for (int ct = 0; ct < 8; ++ct) {
            int col = ct * 16 + l15;
            out[grow * 128 + col] = (vals[ct] - mu) * rs * gamma[col] + beta[col];
        }
    }
}

// ---------------- launcher ----------------
extern "C" void kernel_launch(void* const* d_in, const int* in_sizes, int n_in,
                              void* d_out, int out_size, void* d_ws, size_t ws_size,
                              hipStream_t stream) {
    const float* X     = (const float*)d_in[0];
    const float* TM    = (const float*)d_in[2];
    const float* Wq    = (const float*)d_in[3];
    const float* Wk    = (const float*)d_in[4];
    const float* Wv    = (const float*)d_in[5];
    const float* Wo    = (const float*)d_in[6];
    const float* gamma = (const float*)d_in[7];
    const float* beta  = (const float*)d_in[8];
    float* out = (float*)d_out;

    char* ws = (char*)d_ws;
    const size_t QKV1 = 2097152;             // elems per t per tensor
    const size_t QKV1B = QKV1 * 2;           // 4 MB

    if (ws_size >= WS_BIG) {
        // fused path (confirmed taken in R7): 3 dispatches total
        unsigned short* q3  = (unsigned short*)(ws);
        unsigned short* k3  = (unsigned short*)(ws + 3 * QKV1B);
        unsigned short* v3  = (unsigned short*)(ws + 6 * QKV1B);
        unsigned short* att = (unsigned short*)(ws + 9 * QKV1B);
        k_qkv<<<dim3(32, 4, 3), 256, 0, stream>>>(
            X, Wq, Wk, Wv, q3, k3, v3, 16384, (int)QKV1);
        k_attn<<<dim3(4, 32, 12), 512, 0, stream>>>(
            q3, k3, v3, TM, att, (int)QKV1, 0);
        k_oproj<<<dim3(32, 8), 256, 0, stream>>>(att, Wo, X, gamma, beta, out);
    } else {
        // fallback: per-t loop
        unsigned short* q_ws   = (unsigned short*)(ws);
        unsigned short* k_ws   = (unsigned short*)(ws + QKV1B);
        unsigned short* v_ws   = (unsigned short*)(ws + 2 * QKV1B);
        unsigned short* att_ws = (unsigned short*)(ws + 3 * QKV1B);
        const int tsel[3] = {0, 1, 3};
        for (int t = 0; t < 3; ++t) {
            k_qkv<<<dim3(32, 4, 1), 256, 0, stream>>>(
                X, Wq + (size_t)t * 16384, Wk + (size_t)t * 16384, Wv + (size_t)t * 16384,
                q_ws, k_ws, v_ws, 0, 0);
            k_attn<<<dim3(4, 32, 4), 512, 0, stream>>>(
                q_ws, k_ws, v_ws, TM + (size_t)tsel[t] * 262144, att_ws, 0, t * 128);
        }
        k_oproj<<<dim3(32, 8), 256, 0, stream>>>(att_ws, Wo, X, gamma, beta, out);
    }
}

// Round 10
// 191.000 us; speedup vs baseline: 3.9855x; 1.1382x over previous
//
#include <hip/hip_runtime.h>

// ---------------- problem constants ----------------
// B*P=32, N=512, D=128, H=4, DK=32, T=3 (tm {0,1,3}; tsel(t)=t+(t>>1))
// Inputs f32, OUTPUT f32. ws >= 50.3MB confirmed (fused path, R7/R8).
// R8 post-mortem: k_attn 74us (dense MFMA); k_qkv+k_oproj ~143us dominated by
// per-wave redundant f32->bf16 weight conversion (500x redundant).
// R9: k_prep converts X/W/Wo to bf16 ONCE; _pre GEMM variants stage via plain
// 16B copies. exp via __builtin_amdgcn_exp2f (R9 fix: __exp2f is CUDA-only).

typedef __attribute__((ext_vector_type(8))) short  short8;
typedef __attribute__((ext_vector_type(4))) float  floatx4;

#define WS_BIG   50331648ull                  // q3/k3/v3 (37.7MB) + att (12.6MB)
#define WS_XL    54919168ull                  // + Xb 4MB + Wb 288KB + Wob 96KB
#define QSCALE   0.25503486f                  // (1/sqrt(32)) * log2(e)

__device__ __forceinline__ float b2f(unsigned short u) {
    union { unsigned int i; float f; } v; v.i = ((unsigned int)u) << 16; return v.f;
}
__device__ __forceinline__ unsigned short f2b(float f) {
    union { float f; unsigned int i; } v; v.f = f;
    unsigned int x = v.i;
    return (unsigned short)((x + 0x7fffu + ((x >> 16) & 1u)) >> 16);
}
__device__ __forceinline__ short8 cvt8(const float* p) {
    floatx4 a = *(const floatx4*)p;
    floatx4 b = *(const floatx4*)(p + 4);
    short8 r;
    r[0] = (short)f2b(a[0]); r[1] = (short)f2b(a[1]);
    r[2] = (short)f2b(a[2]); r[3] = (short)f2b(a[3]);
    r[4] = (short)f2b(b[0]); r[5] = (short)f2b(b[1]);
    r[6] = (short)f2b(b[2]); r[7] = (short)f2b(b[3]);
    return r;
}

// ---------------- K0: one-time f32->bf16 conversion of X, Wq/Wk/Wv, Wo --------
// grid 1120 x 256, 8 elems/thread. Segments: X 2,097,152 | Wq/Wk/Wv 49,152 ea | Wo 49,152.
__global__ __launch_bounds__(256) void k_prep(
    const float* __restrict__ X,  const float* __restrict__ Wq,
    const float* __restrict__ Wk, const float* __restrict__ Wv,
    const float* __restrict__ Wo,
    unsigned short* __restrict__ Xb, unsigned short* __restrict__ Wb,
    unsigned short* __restrict__ Wob)
{
    size_t i = ((size_t)blockIdx.x * 256 + threadIdx.x) * 8;
    const float* src; unsigned short* dst; size_t off;
    if      (i < 2097152) { src = X;  dst = Xb;          off = i; }
    else if (i < 2146304) { src = Wq; dst = Wb;          off = i - 2097152; }
    else if (i < 2195456) { src = Wk; dst = Wb + 49152;  off = i - 2146304; }
    else if (i < 2244608) { src = Wv; dst = Wb + 98304;  off = i - 2195456; }
    else                  { src = Wo; dst = Wob;         off = i - 2244608; }
    *(short8*)&dst[off] = cvt8(&src[off]);
}

// ---------------- K1a: QKV projection from pre-converted bf16 ----------------
// grid (bp=32, mt=4, tz=3). Staging = plain 16B copies; zero conversions.
__global__ __launch_bounds__(256) void k_qkv_pre(
    const unsigned short* __restrict__ Xb,   // [32][512][128] bf16
    const unsigned short* __restrict__ Wb,   // [3 qkv][3 t][128][128] bf16
    unsigned short* __restrict__ q_ws,
    unsigned short* __restrict__ k_ws,
    unsigned short* __restrict__ v_ws)
{
    int bp = blockIdx.x, mt = blockIdx.y, tz = blockIdx.z;
    __shared__ unsigned short Xs[128 * 128];     // 32 KB
    int tid = threadIdx.x;
    int lane = tid & 63, wv = tid >> 6;
    int l15 = lane & 15, quad = lane >> 4;

    const unsigned short* Xbase = Xb + ((size_t)bp * 512 + mt * 128) * 128;
    for (int i = 0; i < 8; ++i) {
        int e = (i * 256 + tid) * 8;
        *(short8*)&Xs[e] = *(const short8*)&Xbase[e];
    }
    __syncthreads();

    unsigned short* Osel[3] = { q_ws, k_ws, v_ws };
    for (int qkv = 0; qkv < 3; ++qkv) {
        const unsigned short* Wt = Wb + qkv * 49152 + tz * 16384;
        unsigned short* Ob = Osel[qkv] + (size_t)tz * 2097152
                           + ((size_t)bp * 512 + mt * 128) * 128;
        float sc = (qkv == 0) ? QSCALE : 1.0f;
        for (int ct = 0; ct < 8; ++ct) {
            short8 bfr[4];
            for (int kk = 0; kk < 4; ++kk)
                bfr[kk] = *(const short8*)&Wt[(size_t)(ct * 16 + l15) * 128 + kk * 32 + quad * 8];
            floatx4 acc0 = {0.f, 0.f, 0.f, 0.f};
            floatx4 acc1 = {0.f, 0.f, 0.f, 0.f};
            int rt0 = wv * 2, rt1 = wv * 2 + 1;
            for (int kk = 0; kk < 4; ++kk) {
                short8 a0 = *(const short8*)&Xs[(rt0 * 16 + l15) * 128 + kk * 32 + quad * 8];
                short8 a1 = *(const short8*)&Xs[(rt1 * 16 + l15) * 128 + kk * 32 + quad * 8];
                acc0 = __builtin_amdgcn_mfma_f32_16x16x32_bf16(a0, bfr[kk], acc0, 0, 0, 0);
                acc1 = __builtin_amdgcn_mfma_f32_16x16x32_bf16(a1, bfr[kk], acc1, 0, 0, 0);
            }
            int col = ct * 16 + l15;
            for (int i = 0; i < 4; ++i) {
                Ob[(size_t)(rt0 * 16 + quad * 4 + i) * 128 + col] = f2b(acc0[i] * sc);
                Ob[(size_t)(rt1 * 16 + quad * 4 + i) * 128 + col] = f2b(acc1[i] * sc);
            }
        }
    }
}

// ---------------- K1b: QKV projection, inline-cvt fallback (R8-proven) --------
__global__ __launch_bounds__(256) void k_qkv_cvt(
    const float* __restrict__ X,
    const float* __restrict__ Wq, const float* __restrict__ Wk,
    const float* __restrict__ Wv,
    unsigned short* __restrict__ q_ws, unsigned short* __restrict__ k_ws,
    unsigned short* __restrict__ v_ws,
    int wstride, int ostride)
{
    int bp = blockIdx.x, mt = blockIdx.y, tz = blockIdx.z;
    __shared__ unsigned short Xs[128 * 128];
    int tid = threadIdx.x;
    int lane = tid & 63, wv = tid >> 6;
    int l15 = lane & 15, quad = lane >> 4;

    const float* Xbase = X + ((size_t)bp * 512 + mt * 128) * 128;
    for (int i = 0; i < 8; ++i) {
        int e = (i * 256 + tid) * 8;
        *(short8*)&Xs[e] = cvt8(&Xbase[e]);
    }
    __syncthreads();

    size_t woff = (size_t)tz * wstride;
    size_t ooff = (size_t)tz * ostride;
    const float* Wsel[3] = { Wq + woff, Wk + woff, Wv + woff };
    unsigned short* Osel[3] = { q_ws + ooff, k_ws + ooff, v_ws + ooff };

    for (int qkv = 0; qkv < 3; ++qkv) {
        const float* Wb = Wsel[qkv];
        unsigned short* Ob = Osel[qkv] + ((size_t)bp * 512 + mt * 128) * 128;
        float sc = (qkv == 0) ? QSCALE : 1.0f;
        for (int ct = 0; ct < 8; ++ct) {
            short8 bfr[4];
            for (int kk = 0; kk < 4; ++kk)
                bfr[kk] = cvt8(&Wb[(size_t)(ct * 16 + l15) * 128 + kk * 32 + quad * 8]);
            floatx4 acc0 = {0.f, 0.f, 0.f, 0.f};
            floatx4 acc1 = {0.f, 0.f, 0.f, 0.f};
            int rt0 = wv * 2, rt1 = wv * 2 + 1;
            for (int kk = 0; kk < 4; ++kk) {
                short8 a0 = *(const short8*)&Xs[(rt0 * 16 + l15) * 128 + kk * 32 + quad * 8];
                short8 a1 = *(const short8*)&Xs[(rt1 * 16 + l15) * 128 + kk * 32 + quad * 8];
                acc0 = __builtin_amdgcn_mfma_f32_16x16x32_bf16(a0, bfr[kk], acc0, 0, 0, 0);
                acc1 = __builtin_amdgcn_mfma_f32_16x16x32_bf16(a1, bfr[kk], acc1, 0, 0, 0);
            }
            int col = ct * 16 + l15;
            for (int i = 0; i < 4; ++i) {
                Ob[(size_t)(rt0 * 16 + quad * 4 + i) * 128 + col] = f2b(acc0[i] * sc);
                Ob[(size_t)(rt1 * 16 + quad * 4 + i) * 128 + col] = f2b(acc1[i] * sc);
            }
        }
    }
}

// ---------------- K2: dense MFMA masked attention (R8-proven + exp2) ----------
__global__ __launch_bounds__(512) void k_attn(
    const unsigned short* __restrict__ q_ws,   // bf16, pre-scaled by QSCALE
    const unsigned short* __restrict__ k_ws,
    const unsigned short* __restrict__ v_ws,
    const float* __restrict__ tm,
    unsigned short* __restrict__ att_ws,       // [32][512][384] bf16
    int qkv_stride, int toff0)
{
    int nc = blockIdx.x;
    int bp = blockIdx.y;
    int z  = blockIdx.z;
    int t = z >> 2, h = z & 3;
    size_t qoff = (size_t)t * (size_t)qkv_stride;
    const float* tmt = tm + (size_t)(t + (t >> 1)) * 262144;
    int toff = toff0 + t * 128;

    __shared__ unsigned short Vt[32][516];
    __shared__ unsigned short Ps[8][16][72];

    int tid = threadIdx.x, lane = tid & 63, wv = tid >> 6;
    int l15 = lane & 15, quad = lane >> 4;

    {
        const unsigned short* vp = v_ws + qoff + ((size_t)bp * 512 + tid) * 128 + h * 32;
        short8 a = *(const short8*)vp;
        short8 b = *(const short8*)(vp + 8);
        short8 c = *(const short8*)(vp + 16);
        short8 d = *(const short8*)(vp + 24);
        #pragma unroll
        for (int j = 0; j < 8; ++j) {
            Vt[j][tid]      = (unsigned short)a[j];
            Vt[8 + j][tid]  = (unsigned short)b[j];
            Vt[16 + j][tid] = (unsigned short)c[j];
            Vt[24 + j][tid] = (unsigned short)d[j];
        }
    }
    int n0 = nc * 128 + wv * 16;
    short8 qf = *(const short8*)&q_ws[qoff +
        ((size_t)bp * 512 + n0 + l15) * 128 + h * 32 + quad * 8];
    __syncthreads();

    const unsigned short* Kb = k_ws + qoff + (size_t)bp * 512 * 128 + h * 32;
    floatx4 O0 = {0.f, 0.f, 0.f, 0.f};
    floatx4 O1 = {0.f, 0.f, 0.f, 0.f};
    float za[4] = {0.f, 0.f, 0.f, 0.f};
    const floatx4 zero4 = {0.f, 0.f, 0.f, 0.f};

    for (int c = 0; c < 8; ++c) {
        int mb = c * 64;
        short8 kf0 = *(const short8*)&Kb[(size_t)(mb +  0 + l15) * 128 + quad * 8];
        short8 kf1 = *(const short8*)&Kb[(size_t)(mb + 16 + l15) * 128 + quad * 8];
        short8 kf2 = *(const short8*)&Kb[(size_t)(mb + 32 + l15) * 128 + quad * 8];
        short8 kf3 = *(const short8*)&Kb[(size_t)(mb + 48 + l15) * 128 + quad * 8];
        floatx4 S[4];
        S[0] = __builtin_amdgcn_mfma_f32_16x16x32_bf16(qf, kf0, zero4, 0, 0, 0);
        S[1] = __builtin_amdgcn_mfma_f32_16x16x32_bf16(qf, kf1, zero4, 0, 0, 0);
        S[2] = __builtin_amdgcn_mfma_f32_16x16x32_bf16(qf, kf2, zero4, 0, 0, 0);
        S[3] = __builtin_amdgcn_mfma_f32_16x16x32_bf16(qf, kf3, zero4, 0, 0, 0);

        #pragma unroll
        for (int ti = 0; ti < 4; ++ti) {
            int m = mb + ti * 16 + l15;
            #pragma unroll
            for (int i = 0; i < 4; ++i) {
                float tmv = tmt[(size_t)(n0 + quad * 4 + i) * 512 + m];
                float e = __builtin_amdgcn_exp2f(S[ti][i]);  // Q pre-scaled by log2e
                bool on = (tmv != 0.0f);
                za[i] += on ? e : 0.0f;
                float w = on ? e * tmv : 0.0f;
                Ps[wv][quad * 4 + i][ti * 16 + l15] = f2b(w);
            }
        }
        #pragma unroll
        for (int kc = 0; kc < 2; ++kc) {
            short8 pa  = *(const short8*)&Ps[wv][l15][kc * 32 + quad * 8];
            short8 vb0 = *(const short8*)&Vt[l15][mb + kc * 32 + quad * 8];
            short8 vb1 = *(const short8*)&Vt[16 + l15][mb + kc * 32 + quad * 8];
            O0 = __builtin_amdgcn_mfma_f32_16x16x32_bf16(pa, vb0, O0, 0, 0, 0);
            O1 = __builtin_amdgcn_mfma_f32_16x16x32_bf16(pa, vb1, O1, 0, 0, 0);
        }
    }

    #pragma unroll
    for (int d = 1; d < 16; d <<= 1) {
        #pragma unroll
        for (int i = 0; i < 4; ++i) za[i] += __shfl_xor(za[i], d, 64);
    }
    #pragma unroll
    for (int i = 0; i < 4; ++i) {
        float rz = 1.0f / za[i];
        size_t row = (size_t)bp * 512 + n0 + quad * 4 + i;
        att_ws[row * 384 + toff + h * 32 + l15]      = f2b(O0[i] * rz);
        att_ws[row * 384 + toff + h * 32 + 16 + l15] = f2b(O1[i] * rz);
    }
}

// ---------------- K3a: out-projection from pre-converted Wo -------------------
__global__ __launch_bounds__(256) void k_oproj_pre(
    const unsigned short* __restrict__ att_ws,   // [32][512][384] bf16
    const unsigned short* __restrict__ Wob,      // [128][384] bf16
    const float* __restrict__ X,
    const float* __restrict__ gamma,
    const float* __restrict__ beta,
    float* __restrict__ out)
{
    int bp = blockIdx.x;
    int mt = blockIdx.y;
    __shared__ unsigned short As[64 * 128];
    __shared__ unsigned short Ws[128 * 128];
    int tid = threadIdx.x, lane = tid & 63, wv = tid >> 6;
    int l15 = lane & 15, quad = lane >> 4;

    floatx4 acc[8];
    for (int ct = 0; ct < 8; ++ct) acc[ct] = (floatx4){0.f, 0.f, 0.f, 0.f};
    size_t rowbase = (size_t)bp * 512 + mt * 64;

    for (int kc = 0; kc < 3; ++kc) {
        __syncthreads();
        for (int i = 0; i < 4; ++i) {
            int flat = i * 256 + tid;
            int row = flat >> 4, colg = (flat & 15) * 8;
            *(short8*)&As[row * 128 + colg] =
                *(const short8*)&att_ws[(rowbase + row) * 384 + kc * 128 + colg];
        }
        for (int i = 0; i < 8; ++i) {
            int flat = i * 256 + tid;
            int row = flat >> 4, colg = (flat & 15) * 8;
            *(short8*)&Ws[row * 128 + colg] =
                *(const short8*)&Wob[(size_t)row * 384 + kc * 128 + colg];
        }
        __syncthreads();
        for (int ct = 0; ct < 8; ++ct) {
            for (int kk = 0; kk < 4; ++kk) {
                short8 a = *(const short8*)&As[(wv * 16 + l15) * 128 + kk * 32 + quad * 8];
                short8 b = *(const short8*)&Ws[(ct * 16 + l15) * 128 + kk * 32 + quad * 8];
                acc[ct] = __builtin_amdgcn_mfma_f32_16x16x32_bf16(a, b, acc[ct], 0, 0, 0);
            }
        }
    }

    for (int i = 0; i < 4; ++i) {
        int lrow = wv * 16 + quad * 4 + i;
        size_t grow = rowbase + lrow;
        float vals[8];
        float s = 0.f, sq = 0.f;
        for (int ct = 0; ct < 8; ++ct) {
            int col = ct * 16 + l15;
            float v = acc[ct][i] + X[grow * 128 + col];
            vals[ct] = v;
            s += v; sq += v * v;
        }
        for (int d = 1; d < 16; d <<= 1) {
            s  += __shfl_xor(s, d, 64);
            sq += __shfl_xor(sq, d, 64);
        }
        float mu = s * (1.0f / 128.0f);
        float var = sq * (1.0f / 128.0f) - mu * mu;
        float rs = rsqrtf(var + 1e-5f);
        for (int ct = 0; ct < 8; ++ct) {
            int col = ct * 16 + l15;
            out[grow * 128 + col] = (vals[ct] - mu) * rs * gamma[col] + beta[col];
        }
    }
}

// ---------------- K3b: out-projection, inline-cvt fallback (R8-proven) --------
__global__ __launch_bounds__(256) void k_oproj_cvt(
    const unsigned short* __restrict__ att_ws,
    const float* __restrict__ Wo,
    const float* __restrict__ X,
    const float* __restrict__ gamma,
    const float* __restrict__ beta,
    float* __restrict__ out)
{
    int bp = blockIdx.x;
    int mt = blockIdx.y;
    __shared__ unsigned short As[64 * 128];
    __shared__ unsigned short Ws[128 * 128];
    int tid = threadIdx.x, lane = tid & 63, wv = tid >> 6;
    int l15 = lane & 15, quad = lane >> 4;

    floatx4 acc[8];
    for (int ct = 0; ct < 8; ++ct) acc[ct] = (floatx4){0.f, 0.f, 0.f, 0.f};
    size_t rowbase = (size_t)bp * 512 + mt * 64;

    for (int kc = 0; kc < 3; ++kc) {
        __syncthreads();
        for (int i = 0; i < 4; ++i) {
            int flat = i * 256 + tid;
            int row = flat >> 4, colg = (flat & 15) * 8;
            *(short8*)&As[row * 128 + colg] =
                *(const short8*)&att_ws[(rowbase + row) * 384 + kc * 128 + colg];
        }
        for (int i = 0; i < 8; ++i) {
            int flat = i * 256 + tid;
            int row = flat >> 4, colg = (flat & 15) * 8;
            *(short8*)&Ws[row * 128 + colg] = cvt8(&Wo[(size_t)row * 384 + kc * 128 + colg]);
        }
        __syncthreads();
        for (int ct = 0; ct < 8; ++ct) {
            for (int kk = 0; kk < 4; ++kk) {
                short8 a = *(const short8*)&As[(wv * 16 + l15) * 128 + kk * 32 + quad * 8];
                short8 b = *(const short8*)&Ws[(ct * 16 + l15) * 128 + kk * 32 + quad * 8];
                acc[ct] = __builtin_amdgcn_mfma_f32_16x16x32_bf16(a, b, acc[ct], 0, 0, 0);
            }
        }
    }

    for (int i = 0; i < 4; ++i) {
        int lrow = wv * 16 + quad * 4 + i;
        size_t grow = rowbase + lrow;
        float vals[8];
        float s = 0.f, sq = 0.f;
        for (int ct = 0; ct < 8; ++ct) {
            int col = ct * 16 + l15;
            float v = acc[ct][i] + X[grow * 128 + col];
            vals[ct] = v;
            s += v; sq += v * v;
        }
        for (int d = 1; d < 16; d <<= 1) {
            s  += __shfl_xor(s, d, 64);
            sq += __shfl_xor(sq, d, 64);
        }
        float mu = s * (1.0f / 128.0f);
        float var = sq * (1.0f / 128.0f) - mu * mu;
        float rs = rsqrtf(var + 1e-5f);
        for (int ct = 0; ct < 8; ++ct) {
            int col = ct * 16 + l15;
            out[grow * 128 + col] = (vals[ct] - mu) * rs * gamma[col] + beta[col];
        }
    }
}

// ---------------- launcher ----------------
extern "C" void kernel_launch(void* const* d_in, const int* in_sizes, int n_in,
                              void* d_out, int out_size, void* d_ws, size_t ws_size,
                              hipStream_t stream) {
    const float* X     = (const float*)d_in[0];
    const float* TM    = (const float*)d_in[2];
    const float* Wq    = (const float*)d_in[3];
    const float* Wk    = (const float*)d_in[4];
    const float* Wv    = (const float*)d_in[5];
    const float* Wo    = (const float*)d_in[6];
    const float* gamma = (const float*)d_in[7];
    const float* beta  = (const float*)d_in[8];
    float* out = (float*)d_out;

    char* ws = (char*)d_ws;
    const size_t QKV1 = 2097152;             // elems per t per tensor
    const size_t QKV1B = QKV1 * 2;           // 4 MB

    if (ws_size >= WS_XL) {
        // XL: pre-converted bf16 operands, 4 dispatches
        unsigned short* q3  = (unsigned short*)(ws);
        unsigned short* k3  = (unsigned short*)(ws + 3 * QKV1B);
        unsigned short* v3  = (unsigned short*)(ws + 6 * QKV1B);
        unsigned short* att = (unsigned short*)(ws + 9 * QKV1B);
        unsigned short* Xb  = (unsigned short*)(ws + 50331648ull);
        unsigned short* Wb  = (unsigned short*)(ws + 54525952ull);
        unsigned short* Wob = (unsigned short*)(ws + 54820864ull);
        k_prep<<<dim3(1120), 256, 0, stream>>>(X, Wq, Wk, Wv, Wo, Xb, Wb, Wob);
        k_qkv_pre<<<dim3(32, 4, 3), 256, 0, stream>>>(Xb, Wb, q3, k3, v3);
        k_attn<<<dim3(4, 32, 12), 512, 0, stream>>>(q3, k3, v3, TM, att, (int)QKV1, 0);
        k_oproj_pre<<<dim3(32, 8), 256, 0, stream>>>(att, Wob, X, gamma, beta, out);
    } else if (ws_size >= WS_BIG) {
        // R8-proven fused path, inline conversions
        unsigned short* q3  = (unsigned short*)(ws);
        unsigned short* k3  = (unsigned short*)(ws + 3 * QKV1B);
        unsigned short* v3  = (unsigned short*)(ws + 6 * QKV1B);
        unsigned short* att = (unsigned short*)(ws + 9 * QKV1B);
        k_qkv_cvt<<<dim3(32, 4, 3), 256, 0, stream>>>(
            X, Wq, Wk, Wv, q3, k3, v3, 16384, (int)QKV1);
        k_attn<<<dim3(4, 32, 12), 512, 0, stream>>>(q3, k3, v3, TM, att, (int)QKV1, 0);
        k_oproj_cvt<<<dim3(32, 8), 256, 0, stream>>>(att, Wo, X, gamma, beta, out);
    } else {
        // per-t fallback
        unsigned short* q_ws   = (unsigned short*)(ws);
        unsigned short* k_ws   = (unsigned short*)(ws + QKV1B);
        unsigned short* v_ws   = (unsigned short*)(ws + 2 * QKV1B);
        unsigned short* att_ws = (unsigned short*)(ws + 3 * QKV1B);
        const int tsel[3] = {0, 1, 3};
        for (int t = 0; t < 3; ++t) {
            k_qkv_cvt<<<dim3(32, 4, 1), 256, 0, stream>>>(
                X, Wq + (size_t)t * 16384, Wk + (size_t)t * 16384, Wv + (size_t)t * 16384,
                q_ws, k_ws, v_ws, 0, 0);
            k_attn<<<dim3(4, 32, 4), 512, 0, stream>>>(
                q_ws, k_ws, v_ws, TM + (size_t)tsel[t] * 262144, att_ws, 0, t * 128);
        }
        k_oproj_cvt<<<dim3(32, 8), 256, 0, stream>>>(att_ws, Wo, X, gamma, beta, out);
    }
}